// Round 7
// baseline (470.867 us; speedup 1.0000x reference)
//
#include <hip/hip_runtime.h>
#include <hip/hip_bf16.h>

typedef __attribute__((ext_vector_type(8))) __bf16 bf16x8;
typedef __attribute__((ext_vector_type(4))) float f32x4;
typedef __attribute__((ext_vector_type(16))) float f32x16;

__device__ __forceinline__ unsigned short f2bf(float f) {
    unsigned int u = __float_as_uint(f);
    u += 0x7fff + ((u >> 16) & 1);   // round-to-nearest-even
    return (unsigned short)(u >> 16);
}

__device__ __forceinline__ void gload16(const void* g, void* l) {
    __builtin_amdgcn_global_load_lds(
        (const __attribute__((address_space(1))) void*)g,
        (__attribute__((address_space(3))) void*)l, 16, 0, 0);
}

#define ZOFFB (31040 * 512)   // byte offset of the zero row in every activation buffer

// 247 row-tiles of 128 over the 6 stacked feature maps (31040 rows total)
__device__ __forceinline__ void tile128(int rt, int& rb, int& dim, int& row0, int& aoff) {
    if (rt < 181)      { rb = 0;     dim = 38; row0 = rt * 128;         aoff = 0;     }
    else if (rt < 227) { rb = 23104; dim = 19; row0 = (rt - 181) * 128; aoff = 8664;  }
    else if (rt < 240) { rb = 28880; dim = 10; row0 = (rt - 227) * 128; aoff = 10830; }
    else if (rt < 244) { rb = 30480; dim = 5;  row0 = (rt - 240) * 128; aoff = 11430; }
    else if (rt < 246) { rb = 30880; dim = 3;  row0 = (rt - 244) * 128; aoff = 11580; }
    else               { rb = 31024; dim = 1;  row0 = (rt - 246) * 128; aoff = 11634; }
    row0 += rb;
}

// ---------------------------------------------------------------------------
// Fused weight transform: 8x [256,256,3,3] + 2x [Cout,256,3,3] (pad to 64)
// ---------------------------------------------------------------------------
struct WT { const float* src[10]; };
__global__ void wtrans_all(WT wt, unsigned short* __restrict__ Wb, unsigned short* __restrict__ WF) {
    int idx = blockIdx.x * 256 + threadIdx.x;
    if (idx >= 5013504) return;
    const float* src;
    unsigned short* dst;
    int lo, Cout;
    if (idx < 4718592) {
        int slot = idx / 589824;
        lo = idx - slot * 589824;
        src = wt.src[slot];
        dst = Wb + (size_t)slot * 589824;
        Cout = 256;
    } else {
        int r = idx - 4718592;
        int slot = r / 147456;
        lo = r - slot * 147456;
        src = wt.src[8 + slot];
        dst = WF + (size_t)slot * 147456;
        Cout = slot ? 54 : 24;
    }
    int co = lo / 2304;
    int k  = lo - co * 2304;
    int tap = k >> 8;
    int ci  = k & 255;
    float v = (co < Cout) ? src[(co * 256 + ci) * 9 + tap] : 0.0f;
    dst[lo] = f2bf(v);
}

// ---------------------------------------------------------------------------
// Fused feature transform: 6 maps NCHW fp32 -> [row][256] bf16.
// Extra tail blocks zero the halo row of each activation buffer.
// ---------------------------------------------------------------------------
struct FT { const float* src[6]; unsigned short* halo[4]; int nh; };
__global__ void ftrans_all(FT ft, unsigned short* __restrict__ X0) {
    int idx = blockIdx.x * 256 + threadIdx.x;
    if (idx >= 993280) {
        int idx2 = idx - 993280;           // [0, 1024)
        int buf = idx2 >> 8, off = idx2 & 255;
        if (buf < ft.nh) ft.halo[buf][off] = 0;
        return;
    }
    int row = idx >> 5;
    int c8  = (idx & 31) << 3;
    int m, rb, dim;
    if (row < 23104)      { m = 0; rb = 0;     dim = 38; }
    else if (row < 28880) { m = 1; rb = 23104; dim = 19; }
    else if (row < 30480) { m = 2; rb = 28880; dim = 10; }
    else if (row < 30880) { m = 3; rb = 30480; dim = 5;  }
    else if (row < 31024) { m = 4; rb = 30880; dim = 3;  }
    else                  { m = 5; rb = 31024; dim = 1;  }
    int HW = dim * dim;
    int rel = row - rb;
    int b = rel / HW;
    int hw = rel - b * HW;
    const float* s = ft.src[m] + (size_t)(b * 256 + c8) * HW + hw;
    union { unsigned short u[8]; uint4 v; } tmp;
#pragma unroll
    for (int j = 0; j < 8; ++j) tmp.u[j] = f2bf(s[(size_t)j * HW]);
    *reinterpret_cast<uint4*>(X0 + ((size_t)row << 8) + c8) = tmp.v;
}

// ---------------------------------------------------------------------------
// conv_gemm: 3x3 conv layer C256->C256 (+bias+ReLU), both heads via blockIdx.y.
// 128x256 tile, 512 thr = 8 waves (2M x 4N), 64x64 per wave, 32x32x16 MFMA.
// BK=32, ring-3 LDS (72 KiB -> 2 blocks/CU = 4 waves/SIMD), one barrier/step,
// counted vmcnt(3). A: 1 gload/thr/step; B: 2. 8 ds_read + 8 MFMA per step.
// ---------------------------------------------------------------------------
struct GArgs {
    const unsigned short* X[2];
    const unsigned short* W[2];
    const float* B[2];
    unsigned short* Y[2];
};

__global__ __launch_bounds__(512, 4) void conv_gemm(GArgs ga) {
    __shared__ unsigned char Ls[73728];   // A: 3 slots x 8 KB @0; B: 3 slots x 16 KB @24576

    const int hz = blockIdx.y;
    const unsigned char* __restrict__ Xb = (const unsigned char*)ga.X[hz];
    const unsigned char* __restrict__ Wt = (const unsigned char*)ga.W[hz];
    const float* __restrict__ bias = ga.B[hz];
    unsigned short* __restrict__ Y = ga.Y[hz];

    int rb, dim, row0, aoff;
    tile128(blockIdx.x, rb, dim, row0, aoff);
    const int HWm = dim * dim;
    const int rowEnd = rb + 16 * HWm;

    const int tid = threadIdx.x;
    const int lane = tid & 63, wid = tid >> 6;
    const int l31 = lane & 31, lh = lane >> 5;
    const int wm = wid >> 2, wn = wid & 3;

    // ---- staging geometry: thread covers A row srow (1 load) + B cols srow, srow+128
    const int tq = tid & 3;
    const int srow = tid >> 2;                          // 0..127
    const int xsw = ((tq ^ ((srow >> 1) & 3)) << 4);    // XOR-swizzled quarter (source side)
    const unsigned char* Zr = Xb + ZOFFB + xsw;

    const int g = row0 + srow;
    const bool avv = g < rowEnd;
    int rel = avv ? (g - rb) : 0;
    int bb_ = rel / HWm;
    int hw = rel - bb_ * HWm;
    int ay = hw / dim;
    int ax = hw - ay * dim;

    const unsigned char* bsrc = Wt + (size_t)srow * 4608 + xsw;   // col srow; +589824B = col srow+128

    auto tapA = [&](int tap) -> const unsigned char* {
        int q3 = tap / 3;
        int dy = q3 - 1, dx = tap - q3 * 3 - 1;
        bool v = avv && ((unsigned)(ay + dy) < (unsigned)dim) && ((unsigned)(ax + dx) < (unsigned)dim);
        return v ? Xb + (size_t)(g + dy * dim + dx) * 512 + xsw : Zr;
    };

    // ---- staging dests (linear; swizzle carried by pre-swizzled source)
    const int dA = wid * 1024;            // + slotA(0/8192/16384)
    const int dB = 24576 + wid * 1024;    // + slotB(0/16384/32768), +8192 for cols 128..255

    auto STAGE = [&](const unsigned char* aP, const unsigned char* bT, int kk, int sA_, int sB_) {
        gload16(aP + kk * 64, Ls + sA_ + dA);
        gload16(bT + kk * 64, Ls + sB_ + dB);
        gload16(bT + 589824 + kk * 64, Ls + sB_ + dB + 8192);
    };

    // ---- fragment read offsets (32x32x16): lane l31 = row/col, lh = k-half
    const int ar = wm * 64 + l31;                       // A row (i adds 32 -> +2048B, swz invariant)
    const int rA0 = ar * 64 + (((0 + lh) ^ ((ar >> 1) & 3)) << 4);
    const int rA1 = ar * 64 + (((2 + lh) ^ ((ar >> 1) & 3)) << 4);
    const int cb = wn * 64 + l31;                       // B col
    const int rB0 = 24576 + cb * 64 + (((0 + lh) ^ ((cb >> 1) & 3)) << 4);
    const int rB1 = 24576 + cb * 64 + (((2 + lh) ^ ((cb >> 1) & 3)) << 4);

    f32x16 acc[2][2];
#pragma unroll
    for (int i = 0; i < 2; ++i)
#pragma unroll
        for (int j = 0; j < 2; ++j) acc[i][j] = (f32x16){0.f};

    // ---- prologue: stage steps 0,1
    const unsigned char* aC = tapA(0);
    STAGE(aC, bsrc, 0, 0, 0);
    STAGE(aC, bsrc, 1, 8192, 16384);
    int cA = 0, cB = 0;          // consume slot byte offsets
    int sA = 16384, sB = 32768;  // stage slot byte offsets (t+2)

    // ---- main loop: 9 taps x 8 K-steps of 32 channels (t = tap*8+kc)
#pragma unroll 1
    for (int tap = 0; tap < 9; ++tap) {
        const unsigned char* aN = (tap < 8) ? tapA(tap + 1) : Zr;
        const unsigned char* bT = bsrc + tap * 512;

#pragma unroll
        for (int kc = 0; kc < 8; ++kc) {
            asm volatile("s_waitcnt vmcnt(3)" ::: "memory");   // slot cA/cB landed (this wave)
            __builtin_amdgcn_s_barrier();                      // => all waves' slot data landed

            // stage step t+2 into sA/sB (uniform 3 loads to keep vmcnt counting exact)
            if (tap == 8 && kc >= 6) {
                gload16(Zr, Ls + sA + dA);
                gload16(Zr, Ls + sB + dB);
                gload16(Zr, Ls + sB + dB + 8192);
            } else if (kc < 6) {
                STAGE(aC, bT, kc + 2, sA, sB);
            } else {
                STAGE(aN, bT + 512, kc - 6, sA, sB);
            }

            // LDS -> reg fragments (slot cA/cB)
            bf16x8 af[2][2], bf[2][2];
#pragma unroll
            for (int i = 0; i < 2; ++i) {
                af[i][0] = *(const bf16x8*)(Ls + cA + rA0 + i * 2048);
                af[i][1] = *(const bf16x8*)(Ls + cA + rA1 + i * 2048);
            }
#pragma unroll
            for (int j = 0; j < 2; ++j) {
                bf[j][0] = *(const bf16x8*)(Ls + cB + rB0 + j * 2048);
                bf[j][1] = *(const bf16x8*)(Ls + cB + rB1 + j * 2048);
            }
            asm volatile("s_waitcnt lgkmcnt(0)" ::: "memory");
            __builtin_amdgcn_sched_barrier(0);
            __builtin_amdgcn_s_setprio(1);
#pragma unroll
            for (int kf = 0; kf < 2; ++kf)
#pragma unroll
                for (int i = 0; i < 2; ++i)
#pragma unroll
                    for (int j = 0; j < 2; ++j)
                        acc[i][j] = __builtin_amdgcn_mfma_f32_32x32x16_bf16(af[i][kf], bf[j][kf], acc[i][j], 0, 0, 0);
            __builtin_amdgcn_s_setprio(0);

            cA = (cA == 16384) ? 0 : cA + 8192;
            sA = (sA == 16384) ? 0 : sA + 8192;
            cB = (cB == 32768) ? 0 : cB + 16384;
            sB = (sB == 32768) ? 0 : sB + 16384;
        }
        aC = aN;
    }

    // ---- epilogue: bias + ReLU + bf16 store
    // C/D 32x32 layout: col = lane&31, row = (q&3) + 8*(q>>2) + 4*(lane>>5)
    float bj[2];
#pragma unroll
    for (int j = 0; j < 2; ++j) bj[j] = bias[wn * 64 + j * 32 + l31];
#pragma unroll
    for (int i = 0; i < 2; ++i) {
        int rbase = row0 + wm * 64 + i * 32 + 4 * lh;
#pragma unroll
        for (int q = 0; q < 16; ++q) {
            int orow = rbase + (q & 3) + 8 * (q >> 2);
            if (orow < rowEnd) {
                size_t yb = (size_t)orow * 256 + wn * 64 + l31;
#pragma unroll
                for (int j = 0; j < 2; ++j) {
                    float v = acc[i][j][q] + bj[j];
                    Y[yb + j * 32] = f2bf(fmaxf(v, 0.f));
                }
            }
        }
    }
}

// ---------------------------------------------------------------------------
// conv_final: last conv (Cout pad 64) + bias + anchor-layout scatter, both heads.
// 128x64 tile, 4 waves stacked in M (32x64 each). (r2-verified pipeline.)
// ---------------------------------------------------------------------------
struct FArgs {
    const unsigned short* X[2];
    const unsigned short* W[2];
    const float* B[2];
    float* out;
    int hbase;
};

__global__ __launch_bounds__(256) void conv_final(FArgs fa) {
    __shared__ unsigned char As[2][8192];
    __shared__ unsigned char Bs[2][4096];

    const int zi = blockIdx.z;
    const int hz = zi + fa.hbase;
    const unsigned char* Xb = (const unsigned char*)fa.X[zi];
    const unsigned char* Wt = (const unsigned char*)fa.W[zi];
    const float* bias = fa.B[zi];
    float* out = fa.out;

    int rb, dim, row0, aoff;
    tile128(blockIdx.x, rb, dim, row0, aoff);
    const int HWm = dim * dim;
    const int rowEnd = rb + 16 * HWm;

    const int tid = threadIdx.x;
    const int lane = tid & 63, wid = tid >> 6;
    const int lr = lane & 15, lg = lane >> 4;

    const int swz16 = (((lane & 3) ^ ((lane >> 3) & 3)) << 4);
    const int srow = wid * 16 + (lane >> 2);

    int ay[2], ax[2], arel[2];
    bool av0[2];
#pragma unroll
    for (int it = 0; it < 2; ++it) {
        int r = row0 + it * 64 + srow;
        bool v = r < rowEnd;
        int rel = v ? (r - rb) : 0;
        int b = rel / HWm;
        int hw = rel - b * HWm;
        int y = hw / dim;
        ay[it] = y; ax[it] = hw - y * dim; arel[it] = rel; av0[it] = v;
    }

    const unsigned char* bB = Wt + (size_t)srow * 4608 + swz16;

    const int fsw = ((lg ^ ((lr >> 1) & 3)) << 4);
    const int aRd = (wid * 32 + lr) * 64 + fsw;
    const int bRd = lr * 64 + fsw;
    const int dA0 = wid * 1024;

    f32x4 acc[2][4];
#pragma unroll
    for (int i = 0; i < 2; ++i)
#pragma unroll
        for (int j = 0; j < 4; ++j) acc[i][j] = (f32x4){0.f, 0.f, 0.f, 0.f};

    auto tapPtr = [&](int tap, const unsigned char** aP) {
        int q3 = tap / 3;
        int dy = q3 - 1, dx = tap - q3 * 3 - 1;
#pragma unroll
        for (int it = 0; it < 2; ++it) {
            bool v = av0[it] && ((unsigned)(ay[it] + dy) < (unsigned)dim)
                             && ((unsigned)(ax[it] + dx) < (unsigned)dim);
            int off = v ? (rb + arel[it] + dy * dim + dx) * 512 : ZOFFB;
            aP[it] = Xb + off + swz16;
        }
    };

    const unsigned char* aP[2];
    tapPtr(0, aP);
    gload16(aP[0], &As[0][dA0]);
    gload16(aP[1], &As[0][dA0 + 4096]);
    gload16(bB, &Bs[0][dA0]);
    __syncthreads();

#pragma unroll 1
    for (int tap = 0; tap < 9; ++tap) {
        const unsigned char* aPn[2];
        if (tap < 8) tapPtr(tap + 1, aPn);
        else { aPn[0] = aP[0]; aPn[1] = aP[1]; }
        const unsigned char* bP = bB + tap * 512;

#pragma unroll
        for (int kin = 0; kin < 8; ++kin) {
            const int cur = kin & 1, nxt = cur ^ 1;
            if (kin < 7) {
                gload16(aP[0] + (kin + 1) * 64, &As[nxt][dA0]);
                gload16(aP[1] + (kin + 1) * 64, &As[nxt][dA0 + 4096]);
                gload16(bP + (kin + 1) * 64, &Bs[nxt][dA0]);
            } else if (tap < 8) {
                gload16(aPn[0], &As[nxt][dA0]);
                gload16(aPn[1], &As[nxt][dA0 + 4096]);
                gload16(bP + 512, &Bs[nxt][dA0]);
            }
            bf16x8 af[2], bg[4];
#pragma unroll
            for (int i = 0; i < 2; ++i)
                af[i] = *(const bf16x8*)(&As[cur][0] + aRd + i * 1024);
#pragma unroll
            for (int j = 0; j < 4; ++j)
                bg[j] = *(const bf16x8*)(&Bs[cur][0] + bRd + j * 1024);
#pragma unroll
            for (int i = 0; i < 2; ++i)
#pragma unroll
                for (int j = 0; j < 4; ++j)
                    acc[i][j] = __builtin_amdgcn_mfma_f32_16x16x32_bf16(af[i], bg[j], acc[i][j], 0, 0, 0);
            __syncthreads();
        }
        aP[0] = aPn[0]; aP[1] = aPn[1];
    }

    const int Cout = hz ? 54 : 24;
#pragma unroll
    for (int i = 0; i < 2; ++i) {
        int rbase = row0 + wid * 32 + i * 16 + lg * 4;
#pragma unroll
        for (int r = 0; r < 4; ++r) {
            int orow = rbase + r;
            if (orow < rowEnd) {
                int rel = orow - rb;
                int b = rel / HWm;
                int hw = rel - b * HWm;
#pragma unroll
                for (int j = 0; j < 4; ++j) {
                    int oc = j * 16 + lr;
                    if (oc < Cout) {
                        int q = oc / 6;
                        int s = oc - q * 6;
                        int anchor = aoff + s * HWm + hw;
                        float v = acc[i][j][r] + bias[oc];
                        if (hz)
                            out[744960 + (size_t)b * 104760 + (size_t)q * 11640 + anchor] = v;
                        else
                            out[(size_t)b * 46560 + (size_t)q * 11640 + anchor] = v;
                    }
                }
            }
        }
    }
}

// ---------------------------------------------------------------------------
extern "C" void kernel_launch(void* const* d_in, const int* in_sizes, int n_in,
                              void* d_out, int out_size, void* d_ws, size_t ws_size,
                              hipStream_t stream) {
    (void)in_sizes; (void)n_in; (void)out_size;

    const float* rw[5]  = {(const float*)d_in[6],  (const float*)d_in[8],
                           (const float*)d_in[10], (const float*)d_in[12],
                           (const float*)d_in[14]};
    const float* rbv[5] = {(const float*)d_in[7],  (const float*)d_in[9],
                           (const float*)d_in[11], (const float*)d_in[13],
                           (const float*)d_in[15]};
    const float* cw[5]  = {(const float*)d_in[16], (const float*)d_in[18],
                           (const float*)d_in[20], (const float*)d_in[22],
                           (const float*)d_in[24]};
    const float* cbv[5] = {(const float*)d_in[17], (const float*)d_in[19],
                           (const float*)d_in[21], (const float*)d_in[23],
                           (const float*)d_in[25]};

    const size_t ACTB = 31041ull * 512;
    const size_t WMAT = 589824;
    const size_t WBYTES = 8 * WMAT * 2;
    const size_t WFBYTES = 2 * 147456 * 2;
    const size_t needF = 4 * ACTB + WBYTES + WFBYTES;
    const size_t needS = 3 * ACTB + WBYTES + WFBYTES;

    unsigned char* ws = (unsigned char*)d_ws;
    bool fused = (ws_size >= needF);
    if (!fused && ws_size < needS) return;

    int nact = fused ? 4 : 3;
    unsigned short* act[4];
    for (int i = 0; i < nact; ++i) act[i] = (unsigned short*)(ws + (size_t)i * ACTB);
    unsigned short* Wb = (unsigned short*)(ws + (size_t)nact * ACTB);
    unsigned short* WF = (unsigned short*)(ws + (size_t)nact * ACTB + WBYTES);

    WT wt;
    for (int l = 0; l < 4; ++l) { wt.src[l] = rw[l]; wt.src[4 + l] = cw[l]; }
    wt.src[8] = rw[4]; wt.src[9] = cw[4];
    wtrans_all<<<19584, 256, 0, stream>>>(wt, Wb, WF);

    FT ft;
    for (int i = 0; i < 6; ++i) ft.src[i] = (const float*)d_in[i];
    for (int i = 0; i < 4; ++i)
        ft.halo[i] = (unsigned short*)((unsigned char*)act[i < nact ? i : 0] + ZOFFB);
    ft.nh = nact;
    ftrans_all<<<3884, 256, 0, stream>>>(ft, act[0]);

    const unsigned short* Wr[5], *Wc[5];
    for (int l = 0; l < 4; ++l) {
        Wr[l] = Wb + (size_t)l * WMAT;
        Wc[l] = Wb + (size_t)(4 + l) * WMAT;
    }
    Wr[4] = WF; Wc[4] = WF + 147456;

    if (fused) {
        unsigned short* X0 = act[0];
        unsigned short* P = act[1];
        unsigned short* Q = act[2];
        unsigned short* R = act[3];
        GArgs l1 = {{X0, X0}, {Wr[0], Wc[0]}, {rbv[0], cbv[0]}, {P, Q}};
        GArgs l2 = {{P,  Q},  {Wr[1], Wc[1]}, {rbv[1], cbv[1]}, {X0, R}};
        GArgs l3 = {{X0, R},  {Wr[2], Wc[2]}, {rbv[2], cbv[2]}, {P, Q}};
        GArgs l4 = {{P,  Q},  {Wr[3], Wc[3]}, {rbv[3], cbv[3]}, {X0, R}};
        conv_gemm<<<dim3(247, 2), 512, 0, stream>>>(l1);
        conv_gemm<<<dim3(247, 2), 512, 0, stream>>>(l2);
        conv_gemm<<<dim3(247, 2), 512, 0, stream>>>(l3);
        conv_gemm<<<dim3(247, 2), 512, 0, stream>>>(l4);
        FArgs lf = {{X0, R}, {Wr[4], Wc[4]}, {rbv[4], cbv[4]}, (float*)d_out, 0};
        conv_final<<<dim3(247, 1, 2), 256, 0, stream>>>(lf);
    } else {
        unsigned short* X0 = act[0];
        unsigned short* A1 = act[1];
        unsigned short* A2 = act[2];
        for (int h = 0; h < 2; ++h) {
            const unsigned short* const* W = h ? Wc : Wr;
            const float* const* bs = h ? cbv : rbv;
            GArgs l1 = {{X0, X0}, {W[0], W[0]}, {bs[0], bs[0]}, {A1, A1}};
            GArgs l2 = {{A1, A1}, {W[1], W[1]}, {bs[1], bs[1]}, {A2, A2}};
            GArgs l3 = {{A2, A2}, {W[2], W[2]}, {bs[2], bs[2]}, {A1, A1}};
            GArgs l4 = {{A1, A1}, {W[3], W[3]}, {bs[3], bs[3]}, {A2, A2}};
            conv_gemm<<<dim3(247, 1), 512, 0, stream>>>(l1);
            conv_gemm<<<dim3(247, 1), 512, 0, stream>>>(l2);
            conv_gemm<<<dim3(247, 1), 512, 0, stream>>>(l3);
            conv_gemm<<<dim3(247, 1), 512, 0, stream>>>(l4);
            FArgs lf = {{A2, A2}, {W[4], W[4]}, {bs[4], bs[4]}, (float*)d_out, h};
            conv_final<<<dim3(247, 1, 1), 256, 0, stream>>>(lf);
        }
    }
}